// Round 2
// baseline (216.041 us; speedup 1.0000x reference)
//
#include <hip/hip_runtime.h>

// UngroundedMicroProgram_3504693313604
// x: (S, 8, 6) fp32. Outputs concatenated fp32:
//   action_probs (2, S, 3)  -- both t-planes identical
//   p_values     (2, 28, S) -- plane r = t*28 + i*4 + p*2 + k holds |x[s,0,p]-x[s,i+1,p]|
// EXIST_THRESH = 0.8 is a module constant (not an input).
//
// R2: same as R1 (4 rows/thread, all stores float4 nontemporal) but with a
//     native clang vector type -- __builtin_nontemporal_store rejects HIP's
//     float4 class type.

typedef float f32x4 __attribute__((ext_vector_type(4)));

__global__ __launch_bounds__(256) void ump_kernel4(
    const float* __restrict__ x,
    const float* __restrict__ action,
    const unsigned char* __restrict__ mask,   // bool array; byte-read works for int8 or int32 layouts
    const float* __restrict__ pred_bounds,
    float* __restrict__ out, int S)
{
    const int t  = blockIdx.x * blockDim.x + threadIdx.x;
    const int s4 = t << 2;
    if (s4 >= S) return;

    const float lo0 = pred_bounds[0], hi0 = pred_bounds[1];
    const float lo1 = pred_bounds[2], hi1 = pred_bounds[3];
    const bool  m0  = mask[0] != 0;
    const bool  m1  = mask[1] != 0;
    const float an0 = action[0] / (action[0] + 1e-20f);
    const float an1 = action[1] / (action[1] + 1e-20f);
    const float an2 = action[2] / (action[2] + 1e-20f);

    const size_t Sl = (size_t)S;

    if (s4 + 3 < S) {
        // ---- fast path: 4 consecutive rows, all-vector stores ----
        float d[4][14];
        bool  sat[4];
#pragma unroll
        for (int r = 0; r < 4; ++r) {
            const float* row = x + (size_t)(s4 + r) * 48;
            const float2 a = *(const float2*)(row);   // x[s,0,0], x[s,0,1]
            bool enemy_all = true;
            bool any_sat   = false;
#pragma unroll
            for (int i = 0; i < 7; ++i) {
                const float2 b = *(const float2*)(row + 6 * (i + 1));  // x[s,i+1,{0,1}]
                enemy_all = enemy_all && (b.y > 0.8f);
                const float d0 = fabsf(a.x - b.x);
                const float d1 = fabsf(a.y - b.y);
                d[r][2 * i]     = d0;
                d[r][2 * i + 1] = d1;
                const bool s0 = (d0 >= lo0) && (d0 <= hi0) && (d0 >= lo1) && (d0 <= hi1);
                const bool s1 = (d1 >= lo0) && (d1 <= hi0) && (d1 >= lo1) && (d1 <= hi1);
                any_sat = any_sat || s0 || s1;
            }
            sat[r] = (m0 == (a.x > 0.8f)) && (m1 == enemy_all) && any_sat;
        }

        // action_probs: (2, S, 3). 12 consecutive floats per t-plane -> 3 float4s.
        float ap[12];
#pragma unroll
        for (int r = 0; r < 4; ++r) {
            ap[3 * r + 0] = sat[r] ? an0 : 0.0f;
            ap[3 * r + 1] = sat[r] ? an1 : 0.0f;
            ap[3 * r + 2] = sat[r] ? an2 : 0.0f;
        }
        const f32x4 f0 = { ap[0], ap[1], ap[2],  ap[3]  };
        const f32x4 f1 = { ap[4], ap[5], ap[6],  ap[7]  };
        const f32x4 f2 = { ap[8], ap[9], ap[10], ap[11] };
        float* o0 = out + (size_t)s4 * 3;          // t=0 plane; s4*3*4B = 48*t bytes, 16B-aligned
        __builtin_nontemporal_store(f0, (f32x4*)(o0 + 0));
        __builtin_nontemporal_store(f1, (f32x4*)(o0 + 4));
        __builtin_nontemporal_store(f2, (f32x4*)(o0 + 8));
        float* o1 = o0 + Sl * 3;                   // t=1 plane (identical)
        __builtin_nontemporal_store(f0, (f32x4*)(o1 + 0));
        __builtin_nontemporal_store(f1, (f32x4*)(o1 + 4));
        __builtin_nontemporal_store(f2, (f32x4*)(o1 + 8));

        // p_values: (2, 28, S); plane = t*28 + i*4 + p*2 + k = t*28 + 2*j + k, j = 2i+p.
        // Iterating j ascending, k in {0,1} walks planes 0..27 in order -> q += Sl each store.
        float* q = out + Sl * 6 + s4;              // (6S+s4)*4B, 16B-aligned for S%4==0
#pragma unroll
        for (int tt = 0; tt < 2; ++tt) {
#pragma unroll
            for (int j = 0; j < 14; ++j) {
                const f32x4 v = { d[0][j], d[1][j], d[2][j], d[3][j] };
                __builtin_nontemporal_store(v, (f32x4*)q); q += Sl;   // k = 0
                __builtin_nontemporal_store(v, (f32x4*)q); q += Sl;   // k = 1
            }
        }
    } else {
        // ---- tail path (S % 4 != 0): scalar per-row, identical math ----
        for (int r = 0; r < 4; ++r) {
            const int s = s4 + r;
            if (s >= S) break;
            const float* row = x + (size_t)s * 48;
            const float2 a = *(const float2*)(row);
            float d[14];
            bool enemy_all = true, any_sat = false;
#pragma unroll
            for (int i = 0; i < 7; ++i) {
                const float2 b = *(const float2*)(row + 6 * (i + 1));
                enemy_all = enemy_all && (b.y > 0.8f);
                const float d0 = fabsf(a.x - b.x);
                const float d1 = fabsf(a.y - b.y);
                d[2 * i] = d0; d[2 * i + 1] = d1;
                const bool s0 = (d0 >= lo0) && (d0 <= hi0) && (d0 >= lo1) && (d0 <= hi1);
                const bool s1 = (d1 >= lo0) && (d1 <= hi0) && (d1 >= lo1) && (d1 <= hi1);
                any_sat = any_sat || s0 || s1;
            }
            const bool satisfies = (m0 == (a.x > 0.8f)) && (m1 == enemy_all) && any_sat;
            const float v0 = satisfies ? an0 : 0.0f;
            const float v1 = satisfies ? an1 : 0.0f;
            const float v2 = satisfies ? an2 : 0.0f;

            float* a0 = out + (size_t)s * 3;
            a0[0] = v0; a0[1] = v1; a0[2] = v2;
            float* a1 = out + Sl * 3 + (size_t)s * 3;
            a1[0] = v0; a1[1] = v1; a1[2] = v2;

            float* q = out + Sl * 6 + (size_t)s;
            for (int tt = 0; tt < 2; ++tt)
                for (int j = 0; j < 14; ++j) {
                    const float val = d[j];
                    q[0] = val; q += Sl;
                    q[0] = val; q += Sl;
                }
        }
    }
}

extern "C" void kernel_launch(void* const* d_in, const int* in_sizes, int n_in,
                              void* d_out, int out_size, void* d_ws, size_t ws_size,
                              hipStream_t stream) {
    const float*         x           = (const float*)d_in[0];
    const float*         action      = (const float*)d_in[1];
    const unsigned char* mask        = (const unsigned char*)d_in[2];
    const float*         pred_bounds = (const float*)d_in[3];
    float* out = (float*)d_out;

    const int S = in_sizes[0] / 48;  // 524288
    const int block = 256;
    const int nthreads = (S + 3) / 4;
    const int grid = (nthreads + block - 1) / block;
    ump_kernel4<<<grid, block, 0, stream>>>(x, action, mask, pred_bounds, out, S);
}

// Round 3
// 214.908 us; speedup vs baseline: 1.0053x; 1.0053x over previous
//
#include <hip/hip_runtime.h>

// UngroundedMicroProgram_3504693313604
// x: (S, 8, 6) fp32. Outputs concatenated fp32:
//   action_probs (2, S, 3)  -- both t-planes identical
//   p_values     (2, 28, S) -- plane r = t*28 + i*4 + p*2 + k holds |x[s,0,p]-x[s,i+1,p]|
// EXIST_THRESH = 0.8 is a module constant (not an input).
//
// R3: A/B on the nontemporal hint. Same structure as R2 (4 rows/thread, all
//     stores float4/dwordx4) but PLAIN stores -- let L2 absorb and drain the
//     write stream like the 6.7 TB/s fill kernel does. Loads unchanged
//     (regular dwordx2; intra-row L1 line reuse is load-bearing).

typedef float f32x4 __attribute__((ext_vector_type(4)));

__global__ __launch_bounds__(256) void ump_kernel4(
    const float* __restrict__ x,
    const float* __restrict__ action,
    const unsigned char* __restrict__ mask,   // bool array; byte-read works for int8 or int32 layouts
    const float* __restrict__ pred_bounds,
    float* __restrict__ out, int S)
{
    const int t  = blockIdx.x * blockDim.x + threadIdx.x;
    const int s4 = t << 2;
    if (s4 >= S) return;

    const float lo0 = pred_bounds[0], hi0 = pred_bounds[1];
    const float lo1 = pred_bounds[2], hi1 = pred_bounds[3];
    const bool  m0  = mask[0] != 0;
    const bool  m1  = mask[1] != 0;
    const float an0 = action[0] / (action[0] + 1e-20f);
    const float an1 = action[1] / (action[1] + 1e-20f);
    const float an2 = action[2] / (action[2] + 1e-20f);

    const size_t Sl = (size_t)S;

    if (s4 + 3 < S) {
        // ---- fast path: 4 consecutive rows, all-vector stores ----
        float d[4][14];
        bool  sat[4];
#pragma unroll
        for (int r = 0; r < 4; ++r) {
            const float* row = x + (size_t)(s4 + r) * 48;
            const float2 a = *(const float2*)(row);   // x[s,0,0], x[s,0,1]
            bool enemy_all = true;
            bool any_sat   = false;
#pragma unroll
            for (int i = 0; i < 7; ++i) {
                const float2 b = *(const float2*)(row + 6 * (i + 1));  // x[s,i+1,{0,1}]
                enemy_all = enemy_all && (b.y > 0.8f);
                const float d0 = fabsf(a.x - b.x);
                const float d1 = fabsf(a.y - b.y);
                d[r][2 * i]     = d0;
                d[r][2 * i + 1] = d1;
                const bool s0 = (d0 >= lo0) && (d0 <= hi0) && (d0 >= lo1) && (d0 <= hi1);
                const bool s1 = (d1 >= lo0) && (d1 <= hi0) && (d1 >= lo1) && (d1 <= hi1);
                any_sat = any_sat || s0 || s1;
            }
            sat[r] = (m0 == (a.x > 0.8f)) && (m1 == enemy_all) && any_sat;
        }

        // action_probs: (2, S, 3). 12 consecutive floats per t-plane -> 3 float4s.
        float ap[12];
#pragma unroll
        for (int r = 0; r < 4; ++r) {
            ap[3 * r + 0] = sat[r] ? an0 : 0.0f;
            ap[3 * r + 1] = sat[r] ? an1 : 0.0f;
            ap[3 * r + 2] = sat[r] ? an2 : 0.0f;
        }
        const f32x4 f0 = { ap[0], ap[1], ap[2],  ap[3]  };
        const f32x4 f1 = { ap[4], ap[5], ap[6],  ap[7]  };
        const f32x4 f2 = { ap[8], ap[9], ap[10], ap[11] };
        float* o0 = out + (size_t)s4 * 3;          // t=0 plane; s4*3*4B = 48*t bytes, 16B-aligned
        *(f32x4*)(o0 + 0) = f0;
        *(f32x4*)(o0 + 4) = f1;
        *(f32x4*)(o0 + 8) = f2;
        float* o1 = o0 + Sl * 3;                   // t=1 plane (identical)
        *(f32x4*)(o1 + 0) = f0;
        *(f32x4*)(o1 + 4) = f1;
        *(f32x4*)(o1 + 8) = f2;

        // p_values: (2, 28, S); plane = t*28 + i*4 + p*2 + k = t*28 + 2*j + k, j = 2i+p.
        // Iterating j ascending, k in {0,1} walks planes 0..27 in order -> q += Sl each store.
        float* q = out + Sl * 6 + s4;              // (6S+s4)*4B, 16B-aligned for S%4==0
#pragma unroll
        for (int tt = 0; tt < 2; ++tt) {
#pragma unroll
            for (int j = 0; j < 14; ++j) {
                const f32x4 v = { d[0][j], d[1][j], d[2][j], d[3][j] };
                *(f32x4*)q = v; q += Sl;   // k = 0
                *(f32x4*)q = v; q += Sl;   // k = 1
            }
        }
    } else {
        // ---- tail path (S % 4 != 0): scalar per-row, identical math ----
        for (int r = 0; r < 4; ++r) {
            const int s = s4 + r;
            if (s >= S) break;
            const float* row = x + (size_t)s * 48;
            const float2 a = *(const float2*)(row);
            float d[14];
            bool enemy_all = true, any_sat = false;
#pragma unroll
            for (int i = 0; i < 7; ++i) {
                const float2 b = *(const float2*)(row + 6 * (i + 1));
                enemy_all = enemy_all && (b.y > 0.8f);
                const float d0 = fabsf(a.x - b.x);
                const float d1 = fabsf(a.y - b.y);
                d[2 * i] = d0; d[2 * i + 1] = d1;
                const bool s0 = (d0 >= lo0) && (d0 <= hi0) && (d0 >= lo1) && (d0 <= hi1);
                const bool s1 = (d1 >= lo0) && (d1 <= hi0) && (d1 >= lo1) && (d1 <= hi1);
                any_sat = any_sat || s0 || s1;
            }
            const bool satisfies = (m0 == (a.x > 0.8f)) && (m1 == enemy_all) && any_sat;
            const float v0 = satisfies ? an0 : 0.0f;
            const float v1 = satisfies ? an1 : 0.0f;
            const float v2 = satisfies ? an2 : 0.0f;

            float* a0 = out + (size_t)s * 3;
            a0[0] = v0; a0[1] = v1; a0[2] = v2;
            float* a1 = out + Sl * 3 + (size_t)s * 3;
            a1[0] = v0; a1[1] = v1; a1[2] = v2;

            float* q = out + Sl * 6 + (size_t)s;
            for (int tt = 0; tt < 2; ++tt)
                for (int j = 0; j < 14; ++j) {
                    const float val = d[j];
                    q[0] = val; q += Sl;
                    q[0] = val; q += Sl;
                }
        }
    }
}

extern "C" void kernel_launch(void* const* d_in, const int* in_sizes, int n_in,
                              void* d_out, int out_size, void* d_ws, size_t ws_size,
                              hipStream_t stream) {
    const float*         x           = (const float*)d_in[0];
    const float*         action      = (const float*)d_in[1];
    const unsigned char* mask        = (const unsigned char*)d_in[2];
    const float*         pred_bounds = (const float*)d_in[3];
    float* out = (float*)d_out;

    const int S = in_sizes[0] / 48;  // 524288
    const int block = 256;
    const int nthreads = (S + 3) / 4;
    const int grid = (nthreads + block - 1) / block;
    ump_kernel4<<<grid, block, 0, stream>>>(x, action, mask, pred_bounds, out, S);
}